// Round 4
// baseline (529.836 us; speedup 1.0000x reference)
//
#include <hip/hip_runtime.h>
#include <math.h>

#define KV_HEADS 8
#define Q_HEADS 32
#define HEAD 128
#define BLOCK_SIZE 128
#define CONST_VAL 10.0f
#define F32_TINY 1.1754943508222875e-38f

// ---------------------------------------------------------------------------
// Kernel 1 (full-row streaming): one WG per (seq b, split sp). 512 threads =
// 8 waves; wave w owns kv-head w for ALL positions of the WG's block(s).
// Within a wave, half 0 (lanes 0-31) takes the even position, half 1 the odd;
// lane l32 holds head-dim slice [4*l32, 4*l32+4).
// Per position pair the WG's 8 waves read the ENTIRE 4KB K row and 4KB V row
// contiguously -> each cache block is two clean ~512KB sequential streams
// owned by a single WG (best DRAM granularity). No LDS, no barriers: each
// wave owns its kv-head end-to-end and stores its partial directly.
// Writes UNNORMALIZED partials (sum p*v, sum p); const-normalized softmax
// (p = exp(s - 10)) merges partials by simple addition.
// ---------------------------------------------------------------------------
__global__ __launch_bounds__(512)
void flat_pa_stream8(const float* __restrict__ query,
                     const float* __restrict__ key_cache,
                     const float* __restrict__ value_cache,
                     const int*   __restrict__ block_list,
                     const float* __restrict__ block_bias,
                     float*       __restrict__ ws_acc,  // [B*split][8kh][4q][HEAD]
                     float*       __restrict__ ws_sum,  // [B*split][8kh][4q]
                     int B, int blocks_per_seq, int split)
{
    const int sp   = blockIdx.x;          // split index
    const int b    = blockIdx.y;          // sequence
    const int tid  = threadIdx.x;
    const int kh   = tid >> 6;            // wave = kv head (0..7)
    const int lane = tid & 63;
    const int half = lane >> 5;           // 0 or 1 (even/odd position)
    const int l32  = lane & 31;
    const int dbase = 4 * l32;            // head-dim slice

    const float scale = 0.08838834764831845f;  // 1/sqrt(128)

    // q fragments for the 4 q-heads of this kv head (scale folded in)
    float4 qf[4];
    const float* qrow = query + (size_t)b * (Q_HEADS * HEAD)
                              + (size_t)kh * 4 * HEAD + dbase;
    #pragma unroll
    for (int j = 0; j < 4; ++j) {
        float4 t = *reinterpret_cast<const float4*>(qrow + j * HEAD);
        qf[j] = make_float4(t.x * scale, t.y * scale, t.z * scale, t.w * scale);
    }

    float acc[4][4];                       // [q-head j][d-slice c]
    #pragma unroll
    for (int j = 0; j < 4; ++j)
        #pragma unroll
        for (int c = 0; c < 4; ++c) acc[j][c] = 0.f;
    float psum[4] = {0.f, 0.f, 0.f, 0.f};

    const int per = (blocks_per_seq + split - 1) / split;
    const int i0  = sp * per;
    const int i1  = min(i0 + per, blocks_per_seq);
    const int nb0 = b * blocks_per_seq;
    const int khoff = kh * HEAD;

    for (int i = i0; i < i1; ++i) {
        const int n = nb0 + i;
        const long long blk = block_list[n];
        const float* kbase = key_cache   + blk * (long long)(BLOCK_SIZE * KV_HEADS * HEAD) + khoff;
        const float* vbase = value_cache + blk * (long long)(BLOCK_SIZE * KV_HEADS * HEAD) + khoff;
        const float* bias  = block_bias + (long long)n * BLOCK_SIZE;

        #pragma unroll 4
        for (int it = 0; it < BLOCK_SIZE / 2; ++it) {
            const int s = 2 * it + half;
            const size_t roff = (size_t)s * (KV_HEADS * HEAD) + dbase;
            const float4 kv4 = *reinterpret_cast<const float4*>(kbase + roff);
            const float4 vv4 = *reinterpret_cast<const float4*>(vbase + roff);
            const float  bs  = bias[s];

            float part[4];
            #pragma unroll
            for (int j = 0; j < 4; ++j)
                part[j] = qf[j].x * kv4.x + qf[j].y * kv4.y
                        + qf[j].z * kv4.z + qf[j].w * kv4.w;

            // reduce within each 32-lane half (masks 1..16 stay in-half)
            #pragma unroll
            for (int m = 1; m <= 16; m <<= 1) {
                #pragma unroll
                for (int j = 0; j < 4; ++j)
                    part[j] += __shfl_xor(part[j], m, 64);
            }

            #pragma unroll
            for (int j = 0; j < 4; ++j) {
                const float p = __expf(part[j] + bs - CONST_VAL);
                psum[j]   += p;
                acc[j][0] += p * vv4.x;
                acc[j][1] += p * vv4.y;
                acc[j][2] += p * vv4.z;
                acc[j][3] += p * vv4.w;
            }
        }
    }

    // combine the two halves (disjoint positions)
    #pragma unroll
    for (int j = 0; j < 4; ++j) {
        #pragma unroll
        for (int c = 0; c < 4; ++c)
            acc[j][c] += __shfl_xor(acc[j][c], 32, 64);
        psum[j] += __shfl_xor(psum[j], 32, 64);
    }

    // direct store. half0 stores j 0-1, half1 stores j 2-3 (all lanes hold
    // the full combined acc for every j; split the stores to halve traffic).
    const size_t slot = (size_t)b * split + sp;
    float* wa = ws_acc + slot * (KV_HEADS * 4 * HEAD) + (size_t)kh * (4 * HEAD);
    const int j0 = half * 2;
    #pragma unroll
    for (int t = 0; t < 2; ++t) {
        const int j = j0 + t;
        *reinterpret_cast<float4*>(wa + j * HEAD + dbase) =
            make_float4(acc[j][0], acc[j][1], acc[j][2], acc[j][3]);
    }
    if (l32 == 0) {
        ws_sum[slot * (KV_HEADS * 4) + kh * 4 + j0]     = psum[j0];
        ws_sum[slot * (KV_HEADS * 4) + kh * 4 + j0 + 1] = psum[j0 + 1];
    }
}

// ---------------------------------------------------------------------------
// Kernel 2: merge split partials and normalize. One WG per (kv_head, seq).
// ---------------------------------------------------------------------------
__global__ __launch_bounds__(256)
void flat_pa_reduce8(const float* __restrict__ ws_acc,
                     const float* __restrict__ ws_sum,
                     float*       __restrict__ out,
                     int B, int split)
{
    const int kh  = blockIdx.x;
    const int b   = blockIdx.y;
    const int tid = threadIdx.x;

    for (int o = tid; o < 4 * HEAD; o += 256) {
        const int j = o >> 7;
        const int d = o & 127;
        float a = 0.f, s = 0.f;
        for (int sp = 0; sp < split; ++sp) {
            const size_t slot = (size_t)b * split + sp;
            a += ws_acc[slot * (KV_HEADS * 4 * HEAD) + (size_t)kh * (4 * HEAD) + o];
            s += ws_sum[slot * (KV_HEADS * 4) + kh * 4 + j];
        }
        s += F32_TINY;
        out[(size_t)b * (Q_HEADS * HEAD) + (size_t)(kh * 4 + j) * HEAD + d] = a / s;
    }
}

// ---------------------------------------------------------------------------
// Fallback single-kernel path (only if d_ws too small) - round-0 kernel.
// ---------------------------------------------------------------------------
__global__ __launch_bounds__(256)
void flat_pa_single(const float* __restrict__ query,
                    const float* __restrict__ key_cache,
                    const float* __restrict__ value_cache,
                    const int*   __restrict__ block_list,
                    const float* __restrict__ block_bias,
                    float*       __restrict__ out,
                    int blocks_per_seq)
{
    const int kh   = blockIdx.x;
    const int b    = blockIdx.y;
    const int tid  = threadIdx.x;
    const int wave = tid >> 6;
    const int lane = tid & 63;
    const int half = lane >> 5;
    const int l32  = lane & 31;
    const int dbase = 4 * l32;

    const float scale = 0.08838834764831845f;

    float4 qf[4];
    const float* qrow = query + (size_t)b * (Q_HEADS * HEAD)
                              + (size_t)kh * 4 * HEAD + dbase;
    #pragma unroll
    for (int j = 0; j < 4; ++j) {
        float4 t = *reinterpret_cast<const float4*>(qrow + j * HEAD);
        qf[j] = make_float4(t.x * scale, t.y * scale, t.z * scale, t.w * scale);
    }

    float acc[4][4];
    #pragma unroll
    for (int j = 0; j < 4; ++j)
        #pragma unroll
        for (int c = 0; c < 4; ++c) acc[j][c] = 0.f;
    float psum[4] = {0.f, 0.f, 0.f, 0.f};

    const int nb0 = b * blocks_per_seq;
    for (int i = 0; i < blocks_per_seq; ++i) {
        const int n = nb0 + i;
        const long long blk = block_list[n];
        const float* kbase = key_cache   + blk * (long long)(BLOCK_SIZE * KV_HEADS * HEAD) + kh * HEAD;
        const float* vbase = value_cache + blk * (long long)(BLOCK_SIZE * KV_HEADS * HEAD) + kh * HEAD;
        const float* bias  = block_bias + (long long)n * BLOCK_SIZE;

        #pragma unroll 4
        for (int it = 0; it < 16; ++it) {
            const int s = wave * 32 + 2 * it + half;
            const size_t roff = (size_t)s * (KV_HEADS * HEAD) + dbase;
            const float4 kv4 = *reinterpret_cast<const float4*>(kbase + roff);
            const float4 vv4 = *reinterpret_cast<const float4*>(vbase + roff);
            const float  bs  = bias[s];

            float part[4];
            #pragma unroll
            for (int j = 0; j < 4; ++j)
                part[j] = qf[j].x * kv4.x + qf[j].y * kv4.y
                        + qf[j].z * kv4.z + qf[j].w * kv4.w;
            #pragma unroll
            for (int m = 1; m <= 16; m <<= 1) {
                #pragma unroll
                for (int j = 0; j < 4; ++j)
                    part[j] += __shfl_xor(part[j], m, 64);
            }
            #pragma unroll
            for (int j = 0; j < 4; ++j) {
                const float p = __expf(part[j] + bs - CONST_VAL);
                psum[j]   += p;
                acc[j][0] += p * vv4.x;
                acc[j][1] += p * vv4.y;
                acc[j][2] += p * vv4.z;
                acc[j][3] += p * vv4.w;
            }
        }
    }

    #pragma unroll
    for (int j = 0; j < 4; ++j) {
        #pragma unroll
        for (int c = 0; c < 4; ++c)
            acc[j][c] += __shfl_xor(acc[j][c], 32, 64);
        psum[j] += __shfl_xor(psum[j], 32, 64);
    }

    __shared__ float lds_acc[4][4][HEAD];
    __shared__ float lds_sum[4][4];
    if (half == 0) {
        #pragma unroll
        for (int j = 0; j < 4; ++j)
            #pragma unroll
            for (int c = 0; c < 4; ++c)
                lds_acc[wave][j][dbase + c] = acc[j][c];
        if (l32 == 0) {
            #pragma unroll
            for (int j = 0; j < 4; ++j) lds_sum[wave][j] = psum[j];
        }
    }
    __syncthreads();

    for (int o = tid; o < 4 * HEAD; o += 256) {
        const int j = o >> 7;
        const int d = o & 127;
        const float a = lds_acc[0][j][d] + lds_acc[1][j][d]
                      + lds_acc[2][j][d] + lds_acc[3][j][d];
        const float sum = lds_sum[0][j] + lds_sum[1][j]
                        + lds_sum[2][j] + lds_sum[3][j] + F32_TINY;
        out[(size_t)b * (Q_HEADS * HEAD) + (size_t)(kh * 4 + j) * HEAD + d] = a / sum;
    }
}

extern "C" void kernel_launch(void* const* d_in, const int* in_sizes, int n_in,
                              void* d_out, int out_size, void* d_ws, size_t ws_size,
                              hipStream_t stream) {
    const float* query       = (const float*)d_in[0];
    const float* key_cache   = (const float*)d_in[1];
    const float* value_cache = (const float*)d_in[2];
    const int*   block_list  = (const int*)d_in[3];
    // d_in[4] = block_mapping (one-hot; implied by contiguous grouping)
    const float* block_bias  = (const float*)d_in[5];
    // d_in[6] = block_groups (block i -> seq i / blocks_per_seq)
    float* out = (float*)d_out;

    const int B  = in_sizes[0] / (Q_HEADS * HEAD);
    const int NB = in_sizes[3];
    const int blocks_per_seq = NB / B;

    // 1 block per WG: B*split WGs of 8 waves -> 2 residency rounds (balance)
    int split = blocks_per_seq;
    if (split < 1) split = 1;

    const size_t nslots    = (size_t)B * split;
    const size_t acc_elems = nslots * KV_HEADS * 4 * HEAD;
    const size_t sum_elems = nslots * KV_HEADS * 4;
    const size_t need = (acc_elems + sum_elems) * sizeof(float);

    if (ws_size >= need) {
        float* ws_acc = (float*)d_ws;
        float* ws_sum = ws_acc + acc_elems;
        dim3 grid1(split, B);
        flat_pa_stream8<<<grid1, 512, 0, stream>>>(
            query, key_cache, value_cache, block_list, block_bias,
            ws_acc, ws_sum, B, blocks_per_seq, split);
        dim3 grid2(KV_HEADS, B);
        flat_pa_reduce8<<<grid2, 256, 0, stream>>>(ws_acc, ws_sum, out, B, split);
    } else {
        dim3 grid(KV_HEADS, B);
        flat_pa_single<<<grid, 256, 0, stream>>>(
            query, key_cache, value_cache, block_list, block_bias, out, blocks_per_seq);
    }
}

// Round 5
// 427.254 us; speedup vs baseline: 1.2401x; 1.2401x over previous
//
#include <hip/hip_runtime.h>
#include <math.h>

#define KV_HEADS 8
#define Q_HEADS 32
#define HEAD 128
#define BLOCK_SIZE 128
#define CONST_VAL 10.0f
#define F32_TINY 1.1754943508222875e-38f

// ---------------------------------------------------------------------------
// Kernel 1 (round-3 proven inner loop, unchanged): one WG per
// (seq b, split sp, head-group g). 256 threads = 4 waves; wave w owns kv-head
// kh = g*4 + w for ALL positions of the WG's block(s). Within a wave, half 0
// (lanes 0-31) takes even position, half 1 odd; lane l32 holds head-dim slice
// [4*l32, 4*l32+4). VGPR ~52 -> 8 waves/SIMD (do NOT raise unroll: round-4
// showed unroll 4 crosses the 64-VGPR occupancy cliff and costs ~25%).
// split=blocks_per_seq -> 1 block/WG -> 4096 WGs = 2 residency rounds so
// late finishers are backfilled (tail smoothing).
// Writes UNNORMALIZED partials (sum p*v, sum p); const-normalized softmax
// (p = exp(s - 10)) merges partials by simple addition.
// ---------------------------------------------------------------------------
__global__ __launch_bounds__(256)
void flat_pa_stream(const float* __restrict__ query,
                    const float* __restrict__ key_cache,
                    const float* __restrict__ value_cache,
                    const int*   __restrict__ block_list,
                    const float* __restrict__ block_bias,
                    float*       __restrict__ ws_acc,  // [B*split*2][4w][4q][HEAD]
                    float*       __restrict__ ws_sum,  // [B*split*2][4w][4q]
                    int B, int blocks_per_seq, int split)
{
    const int g    = blockIdx.x & 1;      // head group (kh 0-3 or 4-7)
    const int sp   = blockIdx.x >> 1;     // split index
    const int b    = blockIdx.y;          // sequence
    const int tid  = threadIdx.x;
    const int wave = tid >> 6;            // 0..3
    const int lane = tid & 63;
    const int half = lane >> 5;           // 0 or 1 (even/odd position)
    const int l32  = lane & 31;
    const int dbase = 4 * l32;            // head-dim slice
    const int kh   = g * 4 + wave;        // this wave's kv head

    const float scale = 0.08838834764831845f;  // 1/sqrt(128)

    // q fragments for the 4 q-heads of this kv head (scale folded in)
    float4 qf[4];
    const float* qrow = query + (size_t)b * (Q_HEADS * HEAD)
                              + (size_t)kh * 4 * HEAD + dbase;
    #pragma unroll
    for (int j = 0; j < 4; ++j) {
        float4 t = *reinterpret_cast<const float4*>(qrow + j * HEAD);
        qf[j] = make_float4(t.x * scale, t.y * scale, t.z * scale, t.w * scale);
    }

    float acc[4][4];                       // [q-head j][d-slice c]
    #pragma unroll
    for (int j = 0; j < 4; ++j)
        #pragma unroll
        for (int c = 0; c < 4; ++c) acc[j][c] = 0.f;
    float psum[4] = {0.f, 0.f, 0.f, 0.f};

    const int per = (blocks_per_seq + split - 1) / split;
    const int i0  = sp * per;
    const int i1  = min(i0 + per, blocks_per_seq);
    const int nb0 = b * blocks_per_seq;
    const int khoff = kh * HEAD;

    for (int i = i0; i < i1; ++i) {
        const int n = nb0 + i;
        const long long blk = block_list[n];
        const float* kbase = key_cache   + blk * (long long)(BLOCK_SIZE * KV_HEADS * HEAD) + khoff;
        const float* vbase = value_cache + blk * (long long)(BLOCK_SIZE * KV_HEADS * HEAD) + khoff;
        const float* bias  = block_bias + (long long)n * BLOCK_SIZE;

        #pragma unroll 2
        for (int it = 0; it < BLOCK_SIZE / 2; ++it) {
            const int s = 2 * it + half;
            const size_t roff = (size_t)s * (KV_HEADS * HEAD) + dbase;
            const float4 kv4 = *reinterpret_cast<const float4*>(kbase + roff);
            const float4 vv4 = *reinterpret_cast<const float4*>(vbase + roff);
            const float  bs  = bias[s];

            float part[4];
            #pragma unroll
            for (int j = 0; j < 4; ++j)
                part[j] = qf[j].x * kv4.x + qf[j].y * kv4.y
                        + qf[j].z * kv4.z + qf[j].w * kv4.w;

            // reduce within each 32-lane half (masks 1..16 stay in-half)
            #pragma unroll
            for (int m = 1; m <= 16; m <<= 1) {
                #pragma unroll
                for (int j = 0; j < 4; ++j)
                    part[j] += __shfl_xor(part[j], m, 64);
            }

            #pragma unroll
            for (int j = 0; j < 4; ++j) {
                const float p = __expf(part[j] + bs - CONST_VAL);
                psum[j]   += p;
                acc[j][0] += p * vv4.x;
                acc[j][1] += p * vv4.y;
                acc[j][2] += p * vv4.z;
                acc[j][3] += p * vv4.w;
            }
        }
    }

    // combine the two halves (disjoint positions)
    #pragma unroll
    for (int j = 0; j < 4; ++j) {
        #pragma unroll
        for (int c = 0; c < 4; ++c)
            acc[j][c] += __shfl_xor(acc[j][c], 32, 64);
        psum[j] += __shfl_xor(psum[j], 32, 64);
    }

    // direct store: this wave owns kv-head kh. half0 stores j 0-1, half1 j 2-3.
    const size_t slot = (size_t)(b * split + sp) * 2 + g;
    float* wa = ws_acc + slot * (4 * 4 * HEAD) + (size_t)wave * (4 * HEAD);
    const int j0 = half * 2;
    #pragma unroll
    for (int t = 0; t < 2; ++t) {
        const int j = j0 + t;
        *reinterpret_cast<float4*>(wa + j * HEAD + dbase) =
            make_float4(acc[j][0], acc[j][1], acc[j][2], acc[j][3]);
    }
    if (l32 == 0) {
        ws_sum[slot * 16 + wave * 4 + j0]     = psum[j0];
        ws_sum[slot * 16 + wave * 4 + j0 + 1] = psum[j0 + 1];
    }
}

// ---------------------------------------------------------------------------
// Kernel 2: merge split partials and normalize. One WG per (kv_head, seq).
// float4 reads: lanes 0..127 each own one float4 of the 512-float output.
// ---------------------------------------------------------------------------
__global__ __launch_bounds__(256)
void flat_pa_reduce2(const float* __restrict__ ws_acc,
                     const float* __restrict__ ws_sum,
                     float*       __restrict__ out,
                     int B, int split)
{
    const int kh  = blockIdx.x;
    const int b   = blockIdx.y;
    const int tid = threadIdx.x;
    const int g   = kh >> 2;
    const int w   = kh & 3;

    if (tid >= 128) return;
    const int o4 = tid;            // float4 index within [4q][HEAD] = 128
    const int j  = o4 >> 5;        // q-head

    float4 a = make_float4(0.f, 0.f, 0.f, 0.f);
    float  s = 0.f;
    for (int sp = 0; sp < split; ++sp) {
        const size_t slot = (size_t)(b * split + sp) * 2 + g;
        const float4 t = *reinterpret_cast<const float4*>(
            ws_acc + slot * (4 * 4 * HEAD) + (size_t)w * (4 * HEAD) + 4 * o4);
        a.x += t.x; a.y += t.y; a.z += t.z; a.w += t.w;
        s += ws_sum[slot * 16 + w * 4 + j];
    }
    s += F32_TINY;
    const float inv = 1.0f / s;
    float4 r = make_float4(a.x * inv, a.y * inv, a.z * inv, a.w * inv);
    *reinterpret_cast<float4*>(
        out + (size_t)b * (Q_HEADS * HEAD) + (size_t)(kh * 4) * HEAD + 4 * o4) = r;
}

// ---------------------------------------------------------------------------
// Fallback single-kernel path (only if d_ws too small) - round-0 kernel.
// ---------------------------------------------------------------------------
__global__ __launch_bounds__(256)
void flat_pa_single(const float* __restrict__ query,
                    const float* __restrict__ key_cache,
                    const float* __restrict__ value_cache,
                    const int*   __restrict__ block_list,
                    const float* __restrict__ block_bias,
                    float*       __restrict__ out,
                    int blocks_per_seq)
{
    const int kh   = blockIdx.x;
    const int b    = blockIdx.y;
    const int tid  = threadIdx.x;
    const int wave = tid >> 6;
    const int lane = tid & 63;
    const int half = lane >> 5;
    const int l32  = lane & 31;
    const int dbase = 4 * l32;

    const float scale = 0.08838834764831845f;

    float4 qf[4];
    const float* qrow = query + (size_t)b * (Q_HEADS * HEAD)
                              + (size_t)kh * 4 * HEAD + dbase;
    #pragma unroll
    for (int j = 0; j < 4; ++j) {
        float4 t = *reinterpret_cast<const float4*>(qrow + j * HEAD);
        qf[j] = make_float4(t.x * scale, t.y * scale, t.z * scale, t.w * scale);
    }

    float acc[4][4];
    #pragma unroll
    for (int j = 0; j < 4; ++j)
        #pragma unroll
        for (int c = 0; c < 4; ++c) acc[j][c] = 0.f;
    float psum[4] = {0.f, 0.f, 0.f, 0.f};

    const int nb0 = b * blocks_per_seq;
    for (int i = 0; i < blocks_per_seq; ++i) {
        const int n = nb0 + i;
        const long long blk = block_list[n];
        const float* kbase = key_cache   + blk * (long long)(BLOCK_SIZE * KV_HEADS * HEAD) + kh * HEAD;
        const float* vbase = value_cache + blk * (long long)(BLOCK_SIZE * KV_HEADS * HEAD) + kh * HEAD;
        const float* bias  = block_bias + (long long)n * BLOCK_SIZE;

        #pragma unroll 4
        for (int it = 0; it < 16; ++it) {
            const int s = wave * 32 + 2 * it + half;
            const size_t roff = (size_t)s * (KV_HEADS * HEAD) + dbase;
            const float4 kv4 = *reinterpret_cast<const float4*>(kbase + roff);
            const float4 vv4 = *reinterpret_cast<const float4*>(vbase + roff);
            const float  bs  = bias[s];

            float part[4];
            #pragma unroll
            for (int j = 0; j < 4; ++j)
                part[j] = qf[j].x * kv4.x + qf[j].y * kv4.y
                        + qf[j].z * kv4.z + qf[j].w * kv4.w;
            #pragma unroll
            for (int m = 1; m <= 16; m <<= 1) {
                #pragma unroll
                for (int j = 0; j < 4; ++j)
                    part[j] += __shfl_xor(part[j], m, 64);
            }
            #pragma unroll
            for (int j = 0; j < 4; ++j) {
                const float p = __expf(part[j] + bs - CONST_VAL);
                psum[j]   += p;
                acc[j][0] += p * vv4.x;
                acc[j][1] += p * vv4.y;
                acc[j][2] += p * vv4.z;
                acc[j][3] += p * vv4.w;
            }
        }
    }

    #pragma unroll
    for (int j = 0; j < 4; ++j) {
        #pragma unroll
        for (int c = 0; c < 4; ++c)
            acc[j][c] += __shfl_xor(acc[j][c], 32, 64);
        psum[j] += __shfl_xor(psum[j], 32, 64);
    }

    __shared__ float lds_acc[4][4][HEAD];
    __shared__ float lds_sum[4][4];
    if (half == 0) {
        #pragma unroll
        for (int j = 0; j < 4; ++j)
            #pragma unroll
            for (int c = 0; c < 4; ++c)
                lds_acc[wave][j][dbase + c] = acc[j][c];
        if (l32 == 0) {
            #pragma unroll
            for (int j = 0; j < 4; ++j) lds_sum[wave][j] = psum[j];
        }
    }
    __syncthreads();

    for (int o = tid; o < 4 * HEAD; o += 256) {
        const int j = o >> 7;
        const int d = o & 127;
        const float a = lds_acc[0][j][d] + lds_acc[1][j][d]
                      + lds_acc[2][j][d] + lds_acc[3][j][d];
        const float sum = lds_sum[0][j] + lds_sum[1][j]
                        + lds_sum[2][j] + lds_sum[3][j] + F32_TINY;
        out[(size_t)b * (Q_HEADS * HEAD) + (size_t)(kh * 4 + j) * HEAD + d] = a / sum;
    }
}

extern "C" void kernel_launch(void* const* d_in, const int* in_sizes, int n_in,
                              void* d_out, int out_size, void* d_ws, size_t ws_size,
                              hipStream_t stream) {
    const float* query       = (const float*)d_in[0];
    const float* key_cache   = (const float*)d_in[1];
    const float* value_cache = (const float*)d_in[2];
    const int*   block_list  = (const int*)d_in[3];
    // d_in[4] = block_mapping (one-hot; implied by contiguous grouping)
    const float* block_bias  = (const float*)d_in[5];
    // d_in[6] = block_groups (block i -> seq i / blocks_per_seq)
    float* out = (float*)d_out;

    const int B  = in_sizes[0] / (Q_HEADS * HEAD);
    const int NB = in_sizes[3];
    const int blocks_per_seq = NB / B;

    // 1 block per WG: 2*B*split WGs of 4 waves -> 2 residency rounds (backfill)
    int split = blocks_per_seq;
    if (split < 1) split = 1;

    size_t nslots    = (size_t)B * split * 2;
    size_t acc_elems = nslots * 4 * 4 * HEAD;
    size_t sum_elems = nslots * 16;
    size_t need = (acc_elems + sum_elems) * sizeof(float);

    if (ws_size < need) {
        // fall back to 2 blocks/WG (round-3 footprint)
        split = (blocks_per_seq + 1) / 2;
        if (split < 1) split = 1;
        nslots    = (size_t)B * split * 2;
        acc_elems = nslots * 4 * 4 * HEAD;
        sum_elems = nslots * 16;
        need = (acc_elems + sum_elems) * sizeof(float);
    }

    if (ws_size >= need) {
        float* ws_acc = (float*)d_ws;
        float* ws_sum = ws_acc + acc_elems;
        dim3 grid1(2 * split, B);
        flat_pa_stream<<<grid1, 256, 0, stream>>>(
            query, key_cache, value_cache, block_list, block_bias,
            ws_acc, ws_sum, B, blocks_per_seq, split);
        dim3 grid2(KV_HEADS, B);
        flat_pa_reduce2<<<grid2, 256, 0, stream>>>(ws_acc, ws_sum, out, B, split);
    } else {
        dim3 grid(KV_HEADS, B);
        flat_pa_single<<<grid, 256, 0, stream>>>(
            query, key_cache, value_cache, block_list, block_bias, out, blocks_per_seq);
    }
}

// Round 7
// 408.229 us; speedup vs baseline: 1.2979x; 1.0466x over previous
//
#include <hip/hip_runtime.h>
#include <math.h>

#define KV_HEADS 8
#define Q_HEADS 32
#define HEAD 128
#define BLOCK_SIZE 128
#define CONST_VAL 10.0f
#define F32_TINY 1.1754943508222875e-38f

// ---------------------------------------------------------------------------
// PROVEN round-3 kernel (validated twice, 407us). One WG per
// (seq b, split sp, head-group g). 256 threads = 4 waves; wave w owns kv-head
// kh = g*4 + w for ALL positions of the WG's blocks. Within a wave, half 0
// (lanes 0-31) takes even position, half 1 odd; lane l32 holds head-dim slice
// [4*l32, 4*l32+4). Per position pair the WG's 4 waves read 2KB contiguous.
// VGPR ~52 -> 8 waves/SIMD (unroll 4 crosses the 64-VGPR cliff: round-4,
// -25%). split=(bps+1)/2 -> 2 blocks/WG -> 2048 WGs = 1 residency round
// (round-5: 2 rounds only adds traffic, no tail gain).
// Writes UNNORMALIZED partials (sum p*v, sum p); const-normalized softmax
// (p = exp(s - 10)) merges partials by simple addition.
// ---------------------------------------------------------------------------
__global__ __launch_bounds__(256)
void flat_pa_stream(const float* __restrict__ query,
                    const float* __restrict__ key_cache,
                    const float* __restrict__ value_cache,
                    const int*   __restrict__ block_list,
                    const float* __restrict__ block_bias,
                    float*       __restrict__ ws_acc,  // [B*split*2][4w][4q][HEAD]
                    float*       __restrict__ ws_sum,  // [B*split*2][4w][4q]
                    int B, int blocks_per_seq, int split)
{
    const int g    = blockIdx.x & 1;      // head group (kh 0-3 or 4-7)
    const int sp   = blockIdx.x >> 1;     // split index
    const int b    = blockIdx.y;          // sequence
    const int tid  = threadIdx.x;
    const int wave = tid >> 6;            // 0..3
    const int lane = tid & 63;
    const int half = lane >> 5;           // 0 or 1 (even/odd position)
    const int l32  = lane & 31;
    const int dbase = 4 * l32;            // head-dim slice
    const int kh   = g * 4 + wave;        // this wave's kv head

    const float scale = 0.08838834764831845f;  // 1/sqrt(128)

    // q fragments for the 4 q-heads of this kv head (scale folded in)
    float4 qf[4];
    const float* qrow = query + (size_t)b * (Q_HEADS * HEAD)
                              + (size_t)kh * 4 * HEAD + dbase;
    #pragma unroll
    for (int j = 0; j < 4; ++j) {
        float4 t = *reinterpret_cast<const float4*>(qrow + j * HEAD);
        qf[j] = make_float4(t.x * scale, t.y * scale, t.z * scale, t.w * scale);
    }

    float acc[4][4];                       // [q-head j][d-slice c]
    #pragma unroll
    for (int j = 0; j < 4; ++j)
        #pragma unroll
        for (int c = 0; c < 4; ++c) acc[j][c] = 0.f;
    float psum[4] = {0.f, 0.f, 0.f, 0.f};

    const int per = (blocks_per_seq + split - 1) / split;
    const int i0  = sp * per;
    const int i1  = min(i0 + per, blocks_per_seq);
    const int nb0 = b * blocks_per_seq;
    const int khoff = kh * HEAD;

    for (int i = i0; i < i1; ++i) {
        const int n = nb0 + i;
        const long long blk = block_list[n];
        const float* kbase = key_cache   + blk * (long long)(BLOCK_SIZE * KV_HEADS * HEAD) + khoff;
        const float* vbase = value_cache + blk * (long long)(BLOCK_SIZE * KV_HEADS * HEAD) + khoff;
        const float* bias  = block_bias + (long long)n * BLOCK_SIZE;

        #pragma unroll 2
        for (int it = 0; it < BLOCK_SIZE / 2; ++it) {
            const int s = 2 * it + half;
            const size_t roff = (size_t)s * (KV_HEADS * HEAD) + dbase;
            const float4 kv4 = *reinterpret_cast<const float4*>(kbase + roff);
            const float4 vv4 = *reinterpret_cast<const float4*>(vbase + roff);
            const float  bs  = bias[s];

            float part[4];
            #pragma unroll
            for (int j = 0; j < 4; ++j)
                part[j] = qf[j].x * kv4.x + qf[j].y * kv4.y
                        + qf[j].z * kv4.z + qf[j].w * kv4.w;

            // reduce within each 32-lane half (masks 1..16 stay in-half)
            #pragma unroll
            for (int m = 1; m <= 16; m <<= 1) {
                #pragma unroll
                for (int j = 0; j < 4; ++j)
                    part[j] += __shfl_xor(part[j], m, 64);
            }

            #pragma unroll
            for (int j = 0; j < 4; ++j) {
                const float p = __expf(part[j] + bs - CONST_VAL);
                psum[j]   += p;
                acc[j][0] += p * vv4.x;
                acc[j][1] += p * vv4.y;
                acc[j][2] += p * vv4.z;
                acc[j][3] += p * vv4.w;
            }
        }
    }

    // combine the two halves (disjoint positions)
    #pragma unroll
    for (int j = 0; j < 4; ++j) {
        #pragma unroll
        for (int c = 0; c < 4; ++c)
            acc[j][c] += __shfl_xor(acc[j][c], 32, 64);
        psum[j] += __shfl_xor(psum[j], 32, 64);
    }

    // direct store: this wave owns kv-head kh. half0 stores j 0-1, half1 j 2-3.
    const size_t slot = (size_t)(b * split + sp) * 2 + g;
    float* wa = ws_acc + slot * (4 * 4 * HEAD) + (size_t)wave * (4 * HEAD);
    const int j0 = half * 2;
    #pragma unroll
    for (int t = 0; t < 2; ++t) {
        const int j = j0 + t;
        *reinterpret_cast<float4*>(wa + j * HEAD + dbase) =
            make_float4(acc[j][0], acc[j][1], acc[j][2], acc[j][3]);
    }
    if (l32 == 0) {
        ws_sum[slot * 16 + wave * 4 + j0]     = psum[j0];
        ws_sum[slot * 16 + wave * 4 + j0 + 1] = psum[j0 + 1];
    }
}

// ---------------------------------------------------------------------------
// Kernel 2: merge split partials and normalize. One WG per (kv_head, seq).
// float4 reads (validated in round-5's passing run): lanes 0..127 each own
// one float4 of the 512-float output.
// ---------------------------------------------------------------------------
__global__ __launch_bounds__(256)
void flat_pa_reduce2(const float* __restrict__ ws_acc,
                     const float* __restrict__ ws_sum,
                     float*       __restrict__ out,
                     int B, int split)
{
    const int kh  = blockIdx.x;
    const int b   = blockIdx.y;
    const int tid = threadIdx.x;
    const int g   = kh >> 2;
    const int w   = kh & 3;

    if (tid >= 128) return;
    const int o4 = tid;            // float4 index within [4q][HEAD] = 128
    const int j  = o4 >> 5;        // q-head

    float4 a = make_float4(0.f, 0.f, 0.f, 0.f);
    float  s = 0.f;
    for (int sp = 0; sp < split; ++sp) {
        const size_t slot = (size_t)(b * split + sp) * 2 + g;
        const float4 t = *reinterpret_cast<const float4*>(
            ws_acc + slot * (4 * 4 * HEAD) + (size_t)w * (4 * HEAD) + 4 * o4);
        a.x += t.x; a.y += t.y; a.z += t.z; a.w += t.w;
        s += ws_sum[slot * 16 + w * 4 + j];
    }
    s += F32_TINY;
    const float inv = 1.0f / s;
    float4 r = make_float4(a.x * inv, a.y * inv, a.z * inv, a.w * inv);
    *reinterpret_cast<float4*>(
        out + (size_t)b * (Q_HEADS * HEAD) + (size_t)(kh * 4) * HEAD + 4 * o4) = r;
}

// ---------------------------------------------------------------------------
// Fallback single-kernel path (only if d_ws too small) - round-0 kernel.
// ---------------------------------------------------------------------------
__global__ __launch_bounds__(256)
void flat_pa_single(const float* __restrict__ query,
                    const float* __restrict__ key_cache,
                    const float* __restrict__ value_cache,
                    const int*   __restrict__ block_list,
                    const float* __restrict__ block_bias,
                    float*       __restrict__ out,
                    int blocks_per_seq)
{
    const int kh   = blockIdx.x;
    const int b    = blockIdx.y;
    const int tid  = threadIdx.x;
    const int wave = tid >> 6;
    const int lane = tid & 63;
    const int half = lane >> 5;
    const int l32  = lane & 31;
    const int dbase = 4 * l32;

    const float scale = 0.08838834764831845f;

    float4 qf[4];
    const float* qrow = query + (size_t)b * (Q_HEADS * HEAD)
                              + (size_t)kh * 4 * HEAD + dbase;
    #pragma unroll
    for (int j = 0; j < 4; ++j) {
        float4 t = *reinterpret_cast<const float4*>(qrow + j * HEAD);
        qf[j] = make_float4(t.x * scale, t.y * scale, t.z * scale, t.w * scale);
    }

    float acc[4][4];
    #pragma unroll
    for (int j = 0; j < 4; ++j)
        #pragma unroll
        for (int c = 0; c < 4; ++c) acc[j][c] = 0.f;
    float psum[4] = {0.f, 0.f, 0.f, 0.f};

    const int nb0 = b * blocks_per_seq;
    for (int i = 0; i < blocks_per_seq; ++i) {
        const int n = nb0 + i;
        const long long blk = block_list[n];
        const float* kbase = key_cache   + blk * (long long)(BLOCK_SIZE * KV_HEADS * HEAD) + kh * HEAD;
        const float* vbase = value_cache + blk * (long long)(BLOCK_SIZE * KV_HEADS * HEAD) + kh * HEAD;
        const float* bias  = block_bias + (long long)n * BLOCK_SIZE;

        #pragma unroll 4
        for (int it = 0; it < 16; ++it) {
            const int s = wave * 32 + 2 * it + half;
            const size_t roff = (size_t)s * (KV_HEADS * HEAD) + dbase;
            const float4 kv4 = *reinterpret_cast<const float4*>(kbase + roff);
            const float4 vv4 = *reinterpret_cast<const float4*>(vbase + roff);
            const float  bs  = bias[s];

            float part[4];
            #pragma unroll
            for (int j = 0; j < 4; ++j)
                part[j] = qf[j].x * kv4.x + qf[j].y * kv4.y
                        + qf[j].z * kv4.z + qf[j].w * kv4.w;
            #pragma unroll
            for (int m = 1; m <= 16; m <<= 1) {
                #pragma unroll
                for (int j = 0; j < 4; ++j)
                    part[j] += __shfl_xor(part[j], m, 64);
            }
            #pragma unroll
            for (int j = 0; j < 4; ++j) {
                const float p = __expf(part[j] + bs - CONST_VAL);
                psum[j]   += p;
                acc[j][0] += p * vv4.x;
                acc[j][1] += p * vv4.y;
                acc[j][2] += p * vv4.z;
                acc[j][3] += p * vv4.w;
            }
        }
    }

    #pragma unroll
    for (int j = 0; j < 4; ++j) {
        #pragma unroll
        for (int c = 0; c < 4; ++c)
            acc[j][c] += __shfl_xor(acc[j][c], 32, 64);
        psum[j] += __shfl_xor(psum[j], 32, 64);
    }

    __shared__ float lds_acc[4][4][HEAD];
    __shared__ float lds_sum[4][4];
    if (half == 0) {
        #pragma unroll
        for (int j = 0; j < 4; ++j)
            #pragma unroll
            for (int c = 0; c < 4; ++c)
                lds_acc[wave][j][dbase + c] = acc[j][c];
        if (l32 == 0) {
            #pragma unroll
            for (int j = 0; j < 4; ++j) lds_sum[wave][j] = psum[j];
        }
    }
    __syncthreads();

    for (int o = tid; o < 4 * HEAD; o += 256) {
        const int j = o >> 7;
        const int d = o & 127;
        const float a = lds_acc[0][j][d] + lds_acc[1][j][d]
                      + lds_acc[2][j][d] + lds_acc[3][j][d];
        const float sum = lds_sum[0][j] + lds_sum[1][j]
                        + lds_sum[2][j] + lds_sum[3][j] + F32_TINY;
        out[(size_t)b * (Q_HEADS * HEAD) + (size_t)(kh * 4 + j) * HEAD + d] = a / sum;
    }
}

extern "C" void kernel_launch(void* const* d_in, const int* in_sizes, int n_in,
                              void* d_out, int out_size, void* d_ws, size_t ws_size,
                              hipStream_t stream) {
    const float* query       = (const float*)d_in[0];
    const float* key_cache   = (const float*)d_in[1];
    const float* value_cache = (const float*)d_in[2];
    const int*   block_list  = (const int*)d_in[3];
    // d_in[4] = block_mapping (one-hot; implied by contiguous grouping)
    const float* block_bias  = (const float*)d_in[5];
    // d_in[6] = block_groups (block i -> seq i / blocks_per_seq)
    float* out = (float*)d_out;

    const int B  = in_sizes[0] / (Q_HEADS * HEAD);
    const int NB = in_sizes[3];
    const int blocks_per_seq = NB / B;

    // round-3 proven config: 2 blocks/WG -> 2*B*split WGs = 1 residency round
    int split = (blocks_per_seq + 1) / 2;
    if (split < 1) split = 1;

    const size_t nslots    = (size_t)B * split * 2;
    const size_t acc_elems = nslots * 4 * 4 * HEAD;
    const size_t sum_elems = nslots * 16;
    const size_t need = (acc_elems + sum_elems) * sizeof(float);

    if (ws_size >= need) {
        float* ws_acc = (float*)d_ws;
        float* ws_sum = ws_acc + acc_elems;
        dim3 grid1(2 * split, B);
        flat_pa_stream<<<grid1, 256, 0, stream>>>(
            query, key_cache, value_cache, block_list, block_bias,
            ws_acc, ws_sum, B, blocks_per_seq, split);
        dim3 grid2(KV_HEADS, B);
        flat_pa_reduce2<<<grid2, 256, 0, stream>>>(ws_acc, ws_sum, out, B, split);
    } else {
        dim3 grid(KV_HEADS, B);
        flat_pa_single<<<grid, 256, 0, stream>>>(
            query, key_cache, value_cache, block_list, block_bias, out, blocks_per_seq);
    }
}